// Round 1
// baseline (1836.162 us; speedup 1.0000x reference)
//
#include <hip/hip_runtime.h>

typedef unsigned short u16;
typedef unsigned int u32;
typedef __bf16 bf16;
typedef bf16 bf16x8 __attribute__((ext_vector_type(8)));
typedef float f32x4 __attribute__((ext_vector_type(4)));

#define CIN 384
#define C3 1152
#define NPIX 16384
#define NB 8
#define DH 48
#define IMG 128
#define LDK 40  // BK=32 + 8 pad: frag reads land 2-way (free) on 32 banks

__device__ __forceinline__ u16 f2bf(float f) {
  u32 u = __float_as_uint(f);
  u32 r = (u + 0x7fffu + ((u >> 16) & 1u)) >> 16;  // RNE
  return (u16)r;
}
__device__ __forceinline__ float bf2f(u16 a) { return __uint_as_float(((u32)a) << 16); }
__device__ __forceinline__ u32 pk(u16 a, u16 b) { return (u32)a | ((u32)b << 16); }

// ---------------- K0: LayerNorm stats (mu, rstd per pixel) ----------------
__global__ __launch_bounds__(256) void k_stats(const float* __restrict__ x,
                                               float* __restrict__ mu,
                                               float* __restrict__ rstd) {
  int idx = blockIdx.x * 256 + threadIdx.x;   // B*N = 131072
  int b = idx >> 14, p = idx & (NPIX - 1);
  const float* xp = x + (size_t)b * CIN * NPIX + p;
  float s = 0.f, s2 = 0.f;
#pragma unroll 4
  for (int c = 0; c < CIN; ++c) {
    float v = xp[(size_t)c * NPIX];
    s += v; s2 += v * v;
  }
  float m = s * (1.f / CIN);
  float var = s2 * (1.f / CIN) - m * m;
  mu[idx] = m;
  rstd[idx] = rsqrtf(var + 1e-5f);
}

// ---------------- K1: pointwise conv GEMM with fused LN ----------------
// qkv_pre[b][o][p] = sum_c W[o][c] * xn[b][c][p],  o in [0,1152)
__global__ __launch_bounds__(256) void k_pconv(const float* __restrict__ x,
                                               const float* __restrict__ wp,
                                               const float* __restrict__ lnw,
                                               const float* __restrict__ mu,
                                               const float* __restrict__ rstd,
                                               u16* __restrict__ qkv_pre) {
  __shared__ u16 As[128 * LDK];  // W tile  [o][k], k-contig
  __shared__ u16 Bs[128 * LDK];  // xn tile [p][k], k-contig (transposed on store)
  int blk = blockIdx.x;
  int pt = blk & 127;
  int ot = (blk >> 7) % 9;
  int b = blk / (9 * 128);
  int o0 = ot * 128, p0 = pt * 128;
  int tid = threadIdx.x;
  int lane = tid & 63, wave = tid >> 6;
  int ml = lane & 15, quad = lane >> 4;
  int wm = (wave & 1) * 64, wn = (wave >> 1) * 64;
  int a_row = tid >> 1, a_cs = (tid & 1) * 16;
  int b_p = tid & 127, b_cs = (tid >> 7) * 16;

  const float* xb = x + (size_t)b * CIN * NPIX + p0 + b_p;
  float mu_v = mu[b * NPIX + p0 + b_p];
  float rs_v = rstd[b * NPIX + p0 + b_p];

  f32x4 acc[4][4];
#pragma unroll
  for (int i = 0; i < 4; ++i)
#pragma unroll
    for (int j = 0; j < 4; ++j) acc[i][j] = (f32x4){0.f, 0.f, 0.f, 0.f};

  for (int kc = 0; kc < CIN; kc += 32) {
    {  // A tile: 16 contiguous floats per thread
      const float* ap = wp + (size_t)(o0 + a_row) * CIN + kc + a_cs;
      u16 t[16];
#pragma unroll
      for (int i = 0; i < 16; ++i) t[i] = f2bf(ap[i]);
      uint4 v0 = make_uint4(pk(t[0], t[1]), pk(t[2], t[3]), pk(t[4], t[5]), pk(t[6], t[7]));
      uint4 v1 = make_uint4(pk(t[8], t[9]), pk(t[10], t[11]), pk(t[12], t[13]), pk(t[14], t[15]));
      *(uint4*)&As[a_row * LDK + a_cs] = v0;
      *(uint4*)&As[a_row * LDK + a_cs + 8] = v1;
    }
    {  // B tile: coalesced along p, LN applied, stored transposed [p][k]
      u16 t[16];
#pragma unroll
      for (int i = 0; i < 16; ++i) {
        int c = kc + b_cs + i;
        float xv = xb[(size_t)c * NPIX];
        t[i] = f2bf((xv - mu_v) * rs_v * lnw[c]);
      }
      uint4 v0 = make_uint4(pk(t[0], t[1]), pk(t[2], t[3]), pk(t[4], t[5]), pk(t[6], t[7]));
      uint4 v1 = make_uint4(pk(t[8], t[9]), pk(t[10], t[11]), pk(t[12], t[13]), pk(t[14], t[15]));
      *(uint4*)&Bs[b_p * LDK + b_cs] = v0;
      *(uint4*)&Bs[b_p * LDK + b_cs + 8] = v1;
    }
    __syncthreads();
    bf16x8 af[4], bfr[4];
#pragma unroll
    for (int mt = 0; mt < 4; ++mt)
      af[mt] = *(const bf16x8*)&As[(wm + mt * 16 + ml) * LDK + quad * 8];
#pragma unroll
    for (int nt = 0; nt < 4; ++nt)
      bfr[nt] = *(const bf16x8*)&Bs[(wn + nt * 16 + ml) * LDK + quad * 8];
#pragma unroll
    for (int mt = 0; mt < 4; ++mt)
#pragma unroll
      for (int nt = 0; nt < 4; ++nt)
        acc[mt][nt] = __builtin_amdgcn_mfma_f32_16x16x32_bf16(af[mt], bfr[nt], acc[mt][nt], 0, 0, 0);
    __syncthreads();
  }
#pragma unroll
  for (int mt = 0; mt < 4; ++mt)
#pragma unroll
    for (int nt = 0; nt < 4; ++nt) {
      int o = o0 + wm + mt * 16 + quad * 4;
      int p = p0 + wn + nt * 16 + ml;
      size_t base = ((size_t)(b * C3 + o)) * NPIX + p;
#pragma unroll
      for (int r = 0; r < 4; ++r)
        qkv_pre[base + (size_t)r * NPIX] = f2bf(acc[mt][nt][r]);
    }
}

// ---------------- K2: depthwise 3x3, zero pad ----------------
__global__ __launch_bounds__(256) void k_dconv(const u16* __restrict__ pre,
                                               const float* __restrict__ wd,
                                               u16* __restrict__ post) {
  size_t idx = (size_t)blockIdx.x * 256 + threadIdx.x;  // B*3C*N
  int p = (int)(idx & (NPIX - 1));
  int ch = (int)((idx >> 14) % C3);
  int y = p >> 7, xx = p & 127;
  const u16* pb = pre + (idx - (size_t)p);
  const float* wc = wd + ch * 9;
  float a = 0.f;
#pragma unroll
  for (int ky = 0; ky < 3; ++ky) {
    int yy = y + ky - 1;
    if (yy < 0 || yy >= IMG) continue;
    const u16* row = pb + yy * IMG;
#pragma unroll
    for (int kx = 0; kx < 3; ++kx) {
      int xx2 = xx + kx - 1;
      if (xx2 < 0 || xx2 >= IMG) continue;
      a += bf2f(row[xx2]) * wc[ky * 3 + kx];
    }
  }
  post[idx] = f2bf(a);
}

// ---------------- K3: Q^T K split-K partials ----------------
// score[i][j] = sum_n q[i][n] k[j][n]; 64 chunks of 256 pixels, 1 wave each
__global__ __launch_bounds__(64) void k_score(const u16* __restrict__ post,
                                              float* __restrict__ partial) {
  int blk = blockIdx.x;  // bh*64 + chunk
  int chunk = blk & 63, bh = blk >> 6;
  int b = bh >> 3, h = bh & 7;
  int lane = threadIdx.x;
  int ml = lane & 15, quad = lane >> 4;
  int n0 = chunk * 256;
  const u16* qp[3];
  const u16* kp[3];
#pragma unroll
  for (int t = 0; t < 3; ++t) {
    qp[t] = post + ((size_t)(b * C3 + h * DH + t * 16 + ml)) * NPIX + n0 + quad * 8;
    kp[t] = post + ((size_t)(b * C3 + CIN + h * DH + t * 16 + ml)) * NPIX + n0 + quad * 8;
  }
  f32x4 acc[3][3];
#pragma unroll
  for (int i = 0; i < 3; ++i)
#pragma unroll
    for (int j = 0; j < 3; ++j) acc[i][j] = (f32x4){0.f, 0.f, 0.f, 0.f};
  for (int ks = 0; ks < 256; ks += 32) {
    bf16x8 qf[3], kf[3];
#pragma unroll
    for (int t = 0; t < 3; ++t) {
      qf[t] = *(const bf16x8*)(qp[t] + ks);
      kf[t] = *(const bf16x8*)(kp[t] + ks);
    }
#pragma unroll
    for (int it = 0; it < 3; ++it)
#pragma unroll
      for (int jt = 0; jt < 3; ++jt)
        acc[it][jt] = __builtin_amdgcn_mfma_f32_16x16x32_bf16(qf[it], kf[jt], acc[it][jt], 0, 0, 0);
  }
  float* pp = partial + (size_t)blk * (DH * DH);
#pragma unroll
  for (int it = 0; it < 3; ++it)
#pragma unroll
    for (int jt = 0; jt < 3; ++jt)
#pragma unroll
      for (int r = 0; r < 4; ++r)
        pp[(it * 16 + quad * 4 + r) * DH + jt * 16 + ml] = acc[it][jt][r];
}

// ---------------- K4: reduce partials, softmax, emit score^T (K-padded) ----------------
__global__ __launch_bounds__(256) void k_softmax(const float* __restrict__ partial,
                                                 const float* __restrict__ alpha,
                                                 u16* __restrict__ scoreT) {
  __shared__ float sc[DH * DH];
  __shared__ float pr[DH * DH];
  int bh = blockIdx.x, tid = threadIdx.x;
  const float* pp = partial + (size_t)bh * 64 * (DH * DH);
  for (int e = tid; e < DH * DH; e += 256) {
    float s = 0.f;
    for (int c = 0; c < 64; ++c) s += pp[(size_t)c * (DH * DH) + e];
    sc[e] = s;
  }
  __syncthreads();
  float inv_a = 1.0f / alpha[0];
  if (tid < DH) {
    int i = tid;
    float mx = -1e30f;
    for (int j = 0; j < DH; ++j) mx = fmaxf(mx, sc[i * DH + j] * inv_a);
    float sum = 0.f;
    for (int j = 0; j < DH; ++j) {
      float e = __expf(sc[i * DH + j] * inv_a - mx);
      pr[i * DH + j] = e;
      sum += e;
    }
    float r = 1.f / sum;
    for (int j = 0; j < DH; ++j) pr[i * DH + j] *= r;
  }
  __syncthreads();
  u16* st = scoreT + (size_t)bh * DH * 64;
  for (int e = tid; e < DH * 64; e += 256) {
    int j = e >> 6, i = e & 63;
    st[e] = f2bf(i < DH ? pr[i * DH + j] : 0.f);  // zero-pad K to 64
  }
}

// ---------------- K5: attn^T[j][n] = sum_i score^T[j][i] * v[i][n] ----------------
#define VS_LD 72
__global__ __launch_bounds__(256) void k_attnv(const u16* __restrict__ post,
                                               const u16* __restrict__ scoreT,
                                               u16* __restrict__ attn) {
  __shared__ u16 Vs[128 * VS_LD];  // V^T tile: [n][i], i-contig
  int blk = blockIdx.x;
  int pt = blk & 127, h = (blk >> 7) & 7, b = blk >> 10;
  int p0 = pt * 128;
  int tid = threadIdx.x, lane = tid & 63, wave = tid >> 6;
  int ml = lane & 15, quad = lane >> 4;
  {  // stage V transposed: thread owns one n, 32 i's -> 4x b128 LDS writes
    int n = tid & 127;
    int i0 = (tid >> 7) * 32;
    size_t vbase = ((size_t)(b * C3 + 2 * CIN + h * DH)) * NPIX + p0 + n;
    u16 t[32];
#pragma unroll
    for (int i = 0; i < 32; ++i) t[i] = post[vbase + (size_t)(i0 + i) * NPIX];
#pragma unroll
    for (int q2 = 0; q2 < 4; ++q2) {
      uint4 v = make_uint4(pk(t[q2 * 8 + 0], t[q2 * 8 + 1]), pk(t[q2 * 8 + 2], t[q2 * 8 + 3]),
                           pk(t[q2 * 8 + 4], t[q2 * 8 + 5]), pk(t[q2 * 8 + 6], t[q2 * 8 + 7]));
      *(uint4*)&Vs[n * VS_LD + i0 + q2 * 8] = v;
    }
  }
  __syncthreads();
  const u16* sT = scoreT + (size_t)(b * 8 + h) * (DH * 64);
  int wn = wave * 32;
  f32x4 acc[3][2];
#pragma unroll
  for (int i = 0; i < 3; ++i)
#pragma unroll
    for (int j = 0; j < 2; ++j) acc[i][j] = (f32x4){0.f, 0.f, 0.f, 0.f};
#pragma unroll
  for (int ks = 0; ks < 2; ++ks) {
    bf16x8 a3[3], b2[2];
#pragma unroll
    for (int mt = 0; mt < 3; ++mt)
      a3[mt] = *(const bf16x8*)&sT[(mt * 16 + ml) * 64 + ks * 32 + quad * 8];
#pragma unroll
    for (int nt = 0; nt < 2; ++nt)
      b2[nt] = *(const bf16x8*)&Vs[(wn + nt * 16 + ml) * VS_LD + ks * 32 + quad * 8];
#pragma unroll
    for (int mt = 0; mt < 3; ++mt)
#pragma unroll
      for (int nt = 0; nt < 2; ++nt)
        acc[mt][nt] = __builtin_amdgcn_mfma_f32_16x16x32_bf16(a3[mt], b2[nt], acc[mt][nt], 0, 0, 0);
  }
#pragma unroll
  for (int mt = 0; mt < 3; ++mt)
#pragma unroll
    for (int nt = 0; nt < 2; ++nt)
#pragma unroll
      for (int r = 0; r < 4; ++r) {
        int j = mt * 16 + quad * 4 + r;
        int n = wn + nt * 16 + ml;
        attn[((size_t)(b * CIN + h * DH + j)) * NPIX + p0 + n] = f2bf(acc[mt][nt][r]);
      }
}

// ---------------- K6: output GEMM + residual ----------------
__global__ __launch_bounds__(256) void k_out(const u16* __restrict__ attn,
                                             const float* __restrict__ wo,
                                             const float* __restrict__ x,
                                             float* __restrict__ out) {
  __shared__ u16 As[128 * LDK];
  __shared__ u16 Bs[128 * LDK];
  int blk = blockIdx.x;
  int pt = blk & 127;
  int ot = (blk >> 7) % 3;
  int b = blk / (3 * 128);
  int o0 = ot * 128, p0 = pt * 128;
  int tid = threadIdx.x;
  int lane = tid & 63, wave = tid >> 6;
  int ml = lane & 15, quad = lane >> 4;
  int wm = (wave & 1) * 64, wn = (wave >> 1) * 64;
  int a_row = tid >> 1, a_cs = (tid & 1) * 16;
  int b_p = tid & 127, b_cs = (tid >> 7) * 16;
  const u16* ab = attn + (size_t)b * CIN * NPIX + p0 + b_p;

  f32x4 acc[4][4];
#pragma unroll
  for (int i = 0; i < 4; ++i)
#pragma unroll
    for (int j = 0; j < 4; ++j) acc[i][j] = (f32x4){0.f, 0.f, 0.f, 0.f};

  for (int kc = 0; kc < CIN; kc += 32) {
    {
      const float* ap = wo + (size_t)(o0 + a_row) * CIN + kc + a_cs;
      u16 t[16];
#pragma unroll
      for (int i = 0; i < 16; ++i) t[i] = f2bf(ap[i]);
      uint4 v0 = make_uint4(pk(t[0], t[1]), pk(t[2], t[3]), pk(t[4], t[5]), pk(t[6], t[7]));
      uint4 v1 = make_uint4(pk(t[8], t[9]), pk(t[10], t[11]), pk(t[12], t[13]), pk(t[14], t[15]));
      *(uint4*)&As[a_row * LDK + a_cs] = v0;
      *(uint4*)&As[a_row * LDK + a_cs + 8] = v1;
    }
    {
      u16 t[16];
#pragma unroll
      for (int i = 0; i < 16; ++i) t[i] = ab[(size_t)(kc + b_cs + i) * NPIX];
      uint4 v0 = make_uint4(pk(t[0], t[1]), pk(t[2], t[3]), pk(t[4], t[5]), pk(t[6], t[7]));
      uint4 v1 = make_uint4(pk(t[8], t[9]), pk(t[10], t[11]), pk(t[12], t[13]), pk(t[14], t[15]));
      *(uint4*)&Bs[b_p * LDK + b_cs] = v0;
      *(uint4*)&Bs[b_p * LDK + b_cs + 8] = v1;
    }
    __syncthreads();
    bf16x8 af[4], bfr[4];
#pragma unroll
    for (int mt = 0; mt < 4; ++mt)
      af[mt] = *(const bf16x8*)&As[(wm + mt * 16 + ml) * LDK + quad * 8];
#pragma unroll
    for (int nt = 0; nt < 4; ++nt)
      bfr[nt] = *(const bf16x8*)&Bs[(wn + nt * 16 + ml) * LDK + quad * 8];
#pragma unroll
    for (int mt = 0; mt < 4; ++mt)
#pragma unroll
      for (int nt = 0; nt < 4; ++nt)
        acc[mt][nt] = __builtin_amdgcn_mfma_f32_16x16x32_bf16(af[mt], bfr[nt], acc[mt][nt], 0, 0, 0);
    __syncthreads();
  }
#pragma unroll
  for (int mt = 0; mt < 4; ++mt)
#pragma unroll
    for (int nt = 0; nt < 4; ++nt) {
      int o = o0 + wm + mt * 16 + quad * 4;
      int p = p0 + wn + nt * 16 + ml;
      size_t base = ((size_t)(b * CIN + o)) * NPIX + p;
#pragma unroll
      for (int r = 0; r < 4; ++r) {
        size_t gi = base + (size_t)r * NPIX;
        out[gi] = acc[mt][nt][r] + x[gi];
      }
    }
}

extern "C" void kernel_launch(void* const* d_in, const int* in_sizes, int n_in,
                              void* d_out, int out_size, void* d_ws, size_t ws_size,
                              hipStream_t stream) {
  const float* x = (const float*)d_in[0];
  const float* lnw = (const float*)d_in[1];
  const float* wp = (const float*)d_in[2];
  const float* wd = (const float*)d_in[3];
  const float* wo = (const float*)d_in[4];
  const float* alpha = (const float*)d_in[5];
  float* out = (float*)d_out;

  // ws layout (bytes):
  //   [0, 512K)        mu
  //   [512K, 1M)       rstd
  //   [1M, 1M+302M)    region1: qkv_pre (bf16, 302MB); after dconv it is dead and
  //                    re-used as: attn (bf16, 100.7MB) + partial (fp32, 37.7MB)
  //                    + scoreT (bf16, 0.4MB)
  //   [303,038,464, +302,514,176)  qkv_post (bf16, + 16 channel rows of slack for
  //                                the K-padded V reads of the last (b,h))
  // total = 605,552,640 B
  char* ws = (char*)d_ws;
  float* mu = (float*)ws;
  float* rstd = (float*)(ws + 524288);
  u16* qkv_pre = (u16*)(ws + 1048576);
  u16* attn = qkv_pre;
  float* partial = (float*)(ws + 1048576 + 100663296);
  u16* scoreT = (u16*)(ws + 1048576 + 100663296 + 37748736);
  u16* qkv_post = (u16*)(ws + 303038464);

  hipLaunchKernelGGL(k_stats, dim3(512), dim3(256), 0, stream, x, mu, rstd);
  hipLaunchKernelGGL(k_pconv, dim3(NB * 9 * 128), dim3(256), 0, stream, x, wp, lnw, mu, rstd, qkv_pre);
  hipLaunchKernelGGL(k_dconv, dim3((NB * C3 * NPIX) / 256), dim3(256), 0, stream, qkv_pre, wd, qkv_post);
  hipLaunchKernelGGL(k_score, dim3(64 * 64), dim3(64), 0, stream, qkv_post, partial);
  hipLaunchKernelGGL(k_softmax, dim3(64), dim3(256), 0, stream, partial, alpha, scoreT);
  hipLaunchKernelGGL(k_attnv, dim3(NB * 8 * 128), dim3(256), 0, stream, qkv_post, scoreT, attn);
  hipLaunchKernelGGL(k_out, dim3(NB * 3 * 128), dim3(256), 0, stream, attn, wo, x, out);
}